// Round 20
// baseline (182.713 us; speedup 1.0000x reference)
//
#include <hip/hip_runtime.h>
#include <stdint.h>

#define BATCH 4
#define SEQ   2048
#define CH    1024
#define NH    16
#define HD    64

// 0.125 (1/sqrt(64)) * log2(e): folded into Q so softmax runs in log2 domain.
#define QSCALE 0.18033688011112042f

#define GM 8192
#define GN 1024
#define GK 1024

typedef __attribute__((ext_vector_type(8))) short bf16x8;
typedef __attribute__((ext_vector_type(4))) short bf16x4;
typedef __attribute__((ext_vector_type(4))) float f32x4;

__device__ inline unsigned short f2bf(float f) {
    unsigned u = __float_as_uint(f);
    u += 0x7fff + ((u >> 16) & 1);   // RNE
    return (unsigned short)(u >> 16);
}

__device__ inline float fast_exp2(float x) {
    float r;
    asm("v_exp_f32 %0, %1" : "=v"(r) : "v"(x));
    return r;
}

__device__ inline unsigned cvt_pk_bf16(float lo, float hi) {
    unsigned r;
    asm("v_cvt_pk_bf16_f32 %0, %1, %2" : "=v"(r) : "v"(lo), "v"(hi));
    return r;
}

// D(f32x4) += A(4 bf16: rows(lr) x k=lg*4+j) * B(4 bf16: k=lg*4+j x col=lr)
// Builtin-mediated so the compiler inserts MFMA wait-states (round-9 lesson:
// the hazard recognizer cannot see into inline-asm MFMA -> NaN).
#if __has_builtin(__builtin_amdgcn_mfma_f32_16x16x16bf16_1k)
__device__ inline void mfma16(f32x4& c, bf16x4 a, bf16x4 b) {
    c = __builtin_amdgcn_mfma_f32_16x16x16bf16_1k(a, b, c, 0, 0, 0);
}
#else
__device__ inline void mfma16(f32x4& c, bf16x4 a, bf16x4 b) {
    asm volatile("s_nop 2\n\tv_mfma_f32_16x16x16_bf16 %0, %1, %2, %0"
                 : "+v"(c) : "v"(a), "v"(b));
}
#endif

__device__ inline void gld_lds16(const void* g, void* l) {
    __builtin_amdgcn_global_load_lds((const __attribute__((address_space(1))) void*)g,
                                     (__attribute__((address_space(3))) void*)l,
                                     16, 0, 0);
}

// ---------------- prep: 4x W transpose (fp32 -> bf16^T), one launch ----------
__global__ __launch_bounds__(256) void prep_k(
    const float* __restrict__ Wq, const float* __restrict__ Wk,
    const float* __restrict__ Wv, const float* __restrict__ Wo,
    unsigned short* __restrict__ WqT, unsigned short* __restrict__ WkT,
    unsigned short* __restrict__ WvT, unsigned short* __restrict__ WoT)
{
    __shared__ float tile[32][33];
    const int j     = blockIdx.x >> 10;   // 0..3
    const int local = blockIdx.x & 1023;
    const float* W = (j == 0) ? Wq : (j == 1) ? Wk : (j == 2) ? Wv : Wo;
    unsigned short* Wt = (j == 0) ? WqT : (j == 1) ? WkT : (j == 2) ? WvT : WoT;
    const int bx = (local & 31) * 32;     // n block
    const int by = (local >> 5) * 32;     // k block
    const int tx = threadIdx.x & 31;
    const int ty = threadIdx.x >> 5;      // 0..7
#pragma unroll
    for (int i = 0; i < 32; i += 8)
        tile[ty + i][tx] = W[(size_t)(by + ty + i) * CH + bx + tx];
    __syncthreads();
#pragma unroll
    for (int i = 0; i < 32; i += 8)
        Wt[(size_t)(bx + ty + i) * CH + by + tx] = f2bf(tile[tx][ty + i]);
}

// ---------------- merged QKV projection GEMM: BK=32, DOUBLE-BUFFERED ---------
// attn_k's proven schedule applied to the GEMM: STAGE tile kt+1 into buf^1 at
// loop top (fire-and-forget global_load_lds), compute tile kt, ONE barrier.
// Addressing = round-16-verified BK=32 swizzles (refcheck'd): A chunk c pulls
// logical slot (c&7)^(row&7), frag reads plo=(2lg)^(arow&7), phi=plo^1;
// B stages l=(c&3)^(row&3), reads slot lg^(brow&3). LDS 48 KB (2 blocks/CU).
__global__ __launch_bounds__(256, 2)
void qkv_gemm(const float* __restrict__ Qf, const float* __restrict__ Kf,
              const float* __restrict__ Vf,
              const unsigned short* __restrict__ WqT, const unsigned short* __restrict__ WkT,
              const unsigned short* __restrict__ WvT,
              const float* __restrict__ bq, const float* __restrict__ bk,
              const float* __restrict__ bv,
              unsigned short* __restrict__ Qhb, unsigned short* __restrict__ Khb,
              unsigned short* __restrict__ Vtb)
{
    __shared__ float          As32[2][128 * 32];   // 2 x 16 KB
    __shared__ unsigned short Bs[2][128 * 32];     // 2 x 8 KB
    const int job = blockIdx.y;
    const float* A32          = (job == 0) ? Qf  : (job == 1) ? Kf  : Vf;
    const unsigned short* Bt  = (job == 0) ? WqT : (job == 1) ? WkT : WvT;
    const float* bias         = (job == 0) ? bq  : (job == 1) ? bk  : bv;
    unsigned short* outp      = (job == 0) ? Qhb : (job == 1) ? Khb : Vtb;
    const float oscale        = (job == 0) ? QSCALE : 1.0f;

    const int tid  = threadIdx.x;
    const int lane = tid & 63;
    const int w    = tid >> 6;
    const int nbn  = GN >> 7;                 // 8
    const int nbm  = GM >> 7;                 // 64
    const int xcd  = blockIdx.x & 7;          // XCD m-slab swizzle (bijective)
    const int idx  = blockIdx.x >> 3;
    const int mb   = xcd * (nbm >> 3) + idx / nbn;
    const int nb   = idx % nbn;
    const int m0   = mb << 7;
    const int n0   = nb << 7;
    const int wrow = (w >> 1) << 6;
    const int wcol = (w & 1) << 6;
    const int lr   = lane & 15;
    const int lg   = lane >> 4;

    f32x4 acc[4][4] = {};

#define QSTAGE(K0, B) do {                                                         \
        _Pragma("unroll")                                                          \
        for (int i_ = 0; i_ < 4; ++i_) {                                           \
            int c_ = i_ * 256 + tid;                                               \
            int row_ = c_ >> 3;                                                    \
            int l_   = (c_ & 7) ^ (row_ & 7);                                      \
            gld_lds16(A32 + (size_t)(m0 + row_) * GK + (K0) + l_ * 4,              \
                      (char*)As32[B] + c_ * 16);                                   \
        }                                                                          \
        _Pragma("unroll")                                                          \
        for (int i_ = 0; i_ < 2; ++i_) {                                           \
            int c_ = i_ * 256 + tid;                                               \
            int row_ = c_ >> 2;                                                    \
            int l_   = (c_ & 3) ^ (row_ & 3);                                      \
            gld_lds16(Bt + (size_t)(n0 + row_) * GK + (K0) + l_ * 8,               \
                      (char*)Bs[B] + c_ * 16);                                     \
        }                                                                          \
    } while (0)

    QSTAGE(0, 0);
    __syncthreads();

    const int nkt = GK / 32;   // 32
    for (int kt = 0; kt < nkt; ++kt) {
        if (kt + 1 < nkt) QSTAGE((kt + 1) * 32, (kt + 1) & 1);
        const float*          Ac = As32[kt & 1];
        const unsigned short* Bc = Bs[kt & 1];

        bf16x8 af[4], bfr[4];
#pragma unroll
        for (int f = 0; f < 4; ++f) {
            const int arow = wrow + f * 16 + lr;
            const int plo  = ((lg << 1) ^ (arow & 7));
            const int phi  = plo ^ 1;
            const float* base = Ac + arow * 32;
            f32x4 lo = *(const f32x4*)(base + plo * 4);
            f32x4 hi = *(const f32x4*)(base + phi * 4);
            union { bf16x8 v; unsigned u[4]; } cv;
            cv.u[0] = cvt_pk_bf16(lo[0], lo[1]);
            cv.u[1] = cvt_pk_bf16(lo[2], lo[3]);
            cv.u[2] = cvt_pk_bf16(hi[0], hi[1]);
            cv.u[3] = cvt_pk_bf16(hi[2], hi[3]);
            af[f] = cv.v;
        }
#pragma unroll
        for (int f = 0; f < 4; ++f) {
            const int brow = wcol + f * 16 + lr;
            bfr[f] = *(const bf16x8*)(Bc + brow * 32 + ((lg ^ (brow & 3)) << 3));
        }
#pragma unroll
        for (int i = 0; i < 4; ++i)
#pragma unroll
            for (int j = 0; j < 4; ++j)
                acc[i][j] = __builtin_amdgcn_mfma_f32_16x16x32_bf16(af[i], bfr[j], acc[i][j], 0, 0, 0);
        __syncthreads();
    }
#undef QSTAGE

    float bvals[4];
#pragma unroll
    for (int j = 0; j < 4; ++j) bvals[j] = bias[n0 + wcol + j * 16 + lr];

    if (job < 2) {
#pragma unroll
        for (int i = 0; i < 4; ++i) {
            const int mbase = m0 + wrow + i * 16 + lg * 4;
#pragma unroll
            for (int j = 0; j < 4; ++j) {
                const int n = n0 + wcol + j * 16 + lr;
                const int h = n >> 6, d = n & 63;
#pragma unroll
                for (int r = 0; r < 4; ++r) {
                    const int m = mbase + r;
                    const int b = m >> 11, t = m & 2047;
                    outp[((size_t)(b * NH + h) * SEQ + t) * HD + d] = f2bf((acc[i][j][r] + bvals[j]) * oscale);
                }
            }
        }
    } else {
#pragma unroll
        for (int i = 0; i < 4; ++i) {
            const int mbase = m0 + wrow + i * 16 + lg * 4;
#pragma unroll
            for (int j = 0; j < 4; ++j) {
                const int n = n0 + wcol + j * 16 + lr;
                const int h = n >> 6, d = n & 63;
                const int b = mbase >> 11, t = mbase & 2047;
                union { unsigned short s[4]; uint2 v; } pk;
#pragma unroll
                for (int r = 0; r < 4; ++r) pk.s[r] = f2bf(acc[i][j][r] + bvals[j]);
                *(uint2*)(outp + ((size_t)(b * NH + h) * HD + d) * SEQ + t) = pk.v;
            }
        }
    }
}

// ---------------- output projection GEMM (fp32 out) ----------------
__global__ __launch_bounds__(256, 2)
void gemm_out(const unsigned short* __restrict__ A,
              const unsigned short* __restrict__ Bt,
              const float* __restrict__ bias,
              float* __restrict__ out)
{
    __shared__ unsigned short As[128 * 64];
    __shared__ unsigned short Bs[128 * 64];
    const int tid  = threadIdx.x;
    const int lane = tid & 63;
    const int w    = tid >> 6;
    const int nbn  = GN >> 7;
    const int nbm  = GM >> 7;
    const int xcd  = blockIdx.x & 7;
    const int idx  = blockIdx.x >> 3;
    const int mb   = xcd * (nbm >> 3) + idx / nbn;
    const int nb   = idx % nbn;
    const int m0   = mb << 7;
    const int n0   = nb << 7;
    const int wrow = (w >> 1) << 6;
    const int wcol = (w & 1) << 6;
    const int lr   = lane & 15;
    const int lg   = lane >> 4;

    f32x4 acc[4][4] = {};

    for (int k0 = 0; k0 < GK; k0 += 64) {
#pragma unroll
        for (int i = 0; i < 4; ++i) {
            int chunk = i * 256 + tid;
            int row = chunk >> 3;
            int c8  = (chunk & 7) << 3;
            gld_lds16(A  + (size_t)(m0 + row) * GK + k0 + c8, (char*)As + chunk * 16);
            gld_lds16(Bt + (size_t)(n0 + row) * GK + k0 + c8, (char*)Bs + chunk * 16);
        }
        __syncthreads();
#pragma unroll
        for (int kk = 0; kk < 2; ++kk) {
            bf16x8 af[4], bfr[4];
#pragma unroll
            for (int f = 0; f < 4; ++f)
                af[f] = *(const bf16x8*)(As + (wrow + f * 16 + lr) * 64 + kk * 32 + lg * 8);
#pragma unroll
            for (int f = 0; f < 4; ++f)
                bfr[f] = *(const bf16x8*)(Bs + (wcol + f * 16 + lr) * 64 + kk * 32 + lg * 8);
#pragma unroll
            for (int i = 0; i < 4; ++i)
#pragma unroll
                for (int j = 0; j < 4; ++j)
                    acc[i][j] = __builtin_amdgcn_mfma_f32_16x16x32_bf16(af[i], bfr[j], acc[i][j], 0, 0, 0);
        }
        __syncthreads();
    }

    float bvals[4];
#pragma unroll
    for (int j = 0; j < 4; ++j) bvals[j] = bias[n0 + wcol + j * 16 + lr];

#pragma unroll
    for (int i = 0; i < 4; ++i) {
        const int mbase = m0 + wrow + i * 16 + lg * 4;
#pragma unroll
        for (int j = 0; j < 4; ++j) {
            const int n = n0 + wcol + j * 16 + lr;
#pragma unroll
            for (int r = 0; r < 4; ++r)
                out[(size_t)(mbase + r) * GN + n] = acc[i][j][r] + bvals[j];
        }
    }
}

// ---------------- flash attention (64-row, T13 defer-max THR=8) -------------
__global__ __launch_bounds__(256, 4)
void attn_k(const unsigned short* __restrict__ Qh,   // (BH, T, 64), pre-scaled
            const unsigned short* __restrict__ Kh,   // (BH, T, 64)
            const unsigned short* __restrict__ Vt,   // (BH, 64, T)
            unsigned short* __restrict__ O) {        // (B, T, H*64)
    __shared__ unsigned short Ks[2][64 * 64];
    __shared__ unsigned short Vs[2][64 * 64];   // [d][kv], pair-swizzled
    const int bh    = blockIdx.x;
    const int qtile = 31 - blockIdx.y;          // longest first
    const int q0    = qtile << 6;
    const int tid  = threadIdx.x;
    const int lane = tid & 63;
    const int w    = tid >> 6;
    const int lr   = lane & 15;
    const int lg   = lane >> 4;
    const int qw   = q0 + w * 16;               // wave's first q row

    bf16x4 ones4;
#pragma unroll
    for (int j = 0; j < 4; ++j) ones4[j] = (short)0x3F80;   // bf16 1.0

    bf16x8 qf[2];
#pragma unroll
    for (int kk = 0; kk < 2; ++kk)
        qf[kk] = *(const bf16x8*)(Qh + ((size_t)bh * SEQ + qw + lr) * HD + kk * 32 + lg * 8);

    float mrun = -3e38f;
    f32x4 ot[4] = {};    // O^T: ot[dd] col=lr(q), row=lg*4+r -> d=dd*16+lg*4+r
    f32x4 osum = {};     // all 4 rows equal: sum_k P[q][k]

    const int nkt = qtile + 1;

#define STAGE(KT, B) do {                                                          \
        const int kv_ = (KT) << 6;                                                 \
        _Pragma("unroll")                                                          \
        for (int i_ = 0; i_ < 2; ++i_) {                                           \
            int c_ = i_ * 256 + tid;                                               \
            int row_ = c_ >> 3;                                                    \
            int sk_ = (((c_ & 7) ^ (row_ & 7)) << 3);                              \
            int sv_ = (((c_ & 7) ^ ((row_ >> 1) & 7)) << 3);                       \
            gld_lds16(Kh + ((size_t)bh * SEQ + kv_ + row_) * HD + sk_,             \
                      (char*)Ks[B] + c_ * 16);                                     \
            gld_lds16(Vt + ((size_t)bh * HD + row_) * SEQ + kv_ + sv_,             \
                      (char*)Vs[B] + c_ * 16);                                     \
        }                                                                          \
    } while (0)

    STAGE(0, 0);
    __syncthreads();

    for (int kt = 0; kt < nkt; ++kt) {
        if (kt + 1 < nkt) STAGE(kt + 1, (kt + 1) & 1);
        const unsigned short* Kc = Ks[kt & 1];
        const unsigned short* Vc = Vs[kt & 1];
        const int kv0 = kt << 6;

        // ---- QK^T, swapped operands: s[f] holds S[q=qw+lr][kv0+f*16+lg*4+r] ----
        f32x4 s[4] = {};
#pragma unroll
        for (int kk = 0; kk < 2; ++kk) {
            const int u = (((kk << 2) | lg) ^ (lr & 7)) << 3;
#pragma unroll
            for (int f = 0; f < 4; ++f) {
                bf16x8 kb = *(const bf16x8*)(Kc + (f * 16 + lr) * 64 + u);
                s[f] = __builtin_amdgcn_mfma_f32_16x16x32_bf16(kb, qf[kk], s[f], 0, 0, 0);
            }
        }

        // ---- causal mask (diag tile only) + row max (scalar per lane) ----
        float rmax = -3e38f;
        if (kv0 + 63 <= qw) {
#pragma unroll
            for (int f = 0; f < 4; ++f)
#pragma unroll
                for (int r = 0; r < 4; ++r) rmax = fmaxf(rmax, s[f][r]);
        } else {
            const int q = qw + lr;
#pragma unroll
            for (int f = 0; f < 4; ++f)
#pragma unroll
                for (int r = 0; r < 4; ++r) {
                    const int kv = kv0 + f * 16 + lg * 4 + r;
                    float v = (kv > q) ? -3e38f : s[f][r];
                    s[f][r] = v;
                    rmax = fmaxf(rmax, v);
                }
        }
        // reduce across the 4 lg-groups owning this q row
        rmax = fmaxf(rmax, __shfl_xor(rmax, 16));
        rmax = fmaxf(rmax, __shfl_xor(rmax, 32));

        // ---- T13 deferred rescale: only when max grows past THR=8 ----
        if (!__all(rmax <= mrun + 8.0f)) {
            float mn = fmaxf(mrun, rmax);
            float c  = fast_exp2(mrun - mn);
            mrun = mn;
            osum *= c;
#pragma unroll
            for (int dd = 0; dd < 4; ++dd) ot[dd] *= c;
        }

        // ---- P = 2^(s-m), pack to bf16 in-register, PV + denominator ----
#pragma unroll
        for (int f = 0; f < 4; ++f) {
#pragma unroll
            for (int r = 0; r < 4; ++r)
                s[f][r] = fast_exp2(s[f][r] - mrun);
            union { bf16x4 v; unsigned u[2]; } pb;
            pb.u[0] = cvt_pk_bf16(s[f][0], s[f][1]);
            pb.u[1] = cvt_pk_bf16(s[f][2], s[f][3]);
            mfma16(osum, ones4, pb.v);
#pragma unroll
            for (int dd = 0; dd < 4; ++dd) {
                const int vcol = ((((f << 1) | (lg >> 1)) ^ (lr >> 1)) << 3) | ((lg & 1) << 2);
                bf16x4 va = *(const bf16x4*)(Vc + (dd * 16 + lr) * 64 + vcol);
                mfma16(ot[dd], va, pb.v);
            }
        }
        __syncthreads();
    }
#undef STAGE

    const int b = bh >> 4, h = bh & 15;
    const float inv = 1.0f / osum[0];
    const int t = qw + lr;
#pragma unroll
    for (int dd = 0; dd < 4; ++dd) {
        union { unsigned short s4[4]; uint2 v; } pk;
#pragma unroll
        for (int r = 0; r < 4; ++r) pk.s4[r] = f2bf(ot[dd][r] * inv);
        *(uint2*)(O + ((size_t)b * SEQ + t) * CH + h * HD + dd * 16 + lg * 4) = pk.v;
    }
}

extern "C" void kernel_launch(void* const* d_in, const int* in_sizes, int n_in,
                              void* d_out, int out_size, void* d_ws, size_t ws_size,
                              hipStream_t stream) {
    const float* Q  = (const float*)d_in[0];
    const float* K  = (const float*)d_in[1];
    const float* V  = (const float*)d_in[2];
    // d_in[3] = mask: always causal triu(k=1); applied analytically in attn_k
    const float* Wq = (const float*)d_in[4];
    const float* bq = (const float*)d_in[5];
    const float* Wk = (const float*)d_in[6];
    const float* bk = (const float*)d_in[7];
    const float* Wv = (const float*)d_in[8];
    const float* bv = (const float*)d_in[9];
    const float* Wo = (const float*)d_in[10];
    const float* bo = (const float*)d_in[11];
    float* out = (float*)d_out;

    const size_t SZ_ACT = (size_t)BATCH * SEQ * CH;  // 8388608
    const size_t SZ_W   = (size_t)CH * CH;           // 1048576

    char* p = (char*)d_ws;
    unsigned short* WqT = (unsigned short*)p; p += SZ_W * 2;
    unsigned short* WkT = (unsigned short*)p; p += SZ_W * 2;
    unsigned short* WvT = (unsigned short*)p; p += SZ_W * 2;
    unsigned short* WoT = (unsigned short*)p; p += SZ_W * 2;
    unsigned short* Qhb = (unsigned short*)p; p += SZ_ACT * 2;
    unsigned short* Khb = (unsigned short*)p; p += SZ_ACT * 2;
    unsigned short* Vtb = (unsigned short*)p; p += SZ_ACT * 2;
    unsigned short* Ob  = (unsigned short*)p; p += SZ_ACT * 2;

    prep_k<<<4096, 256, 0, stream>>>(Wq, Wk, Wv, Wo, WqT, WkT, WvT, WoT);

    qkv_gemm<<<dim3((GM / 128) * (GN / 128), 3), 256, 0, stream>>>(
        Q, K, V, WqT, WkT, WvT, bq, bk, bv, Qhb, Khb, Vtb);

    attn_k<<<dim3(BATCH * NH, SEQ / 64), 256, 0, stream>>>(Qhb, Khb, Vtb, Ob);

    gemm_out<<<(GM / 128) * (GN / 128), 256, 0, stream>>>(Ob, WoT, bo, out);
}

// Round 21
// 180.885 us; speedup vs baseline: 1.0101x; 1.0101x over previous
//
#include <hip/hip_runtime.h>
#include <stdint.h>

#define BATCH 4
#define SEQ   2048
#define CH    1024
#define NH    16
#define HD    64

// 0.125 (1/sqrt(64)) * log2(e): folded into Q so softmax runs in log2 domain.
#define QSCALE 0.18033688011112042f

#define GM 8192
#define GN 1024
#define GK 1024

typedef __attribute__((ext_vector_type(8))) short bf16x8;
typedef __attribute__((ext_vector_type(4))) short bf16x4;
typedef __attribute__((ext_vector_type(4))) float f32x4;

__device__ inline unsigned short f2bf(float f) {
    unsigned u = __float_as_uint(f);
    u += 0x7fff + ((u >> 16) & 1);   // RNE
    return (unsigned short)(u >> 16);
}

__device__ inline float fast_exp2(float x) {
    float r;
    asm("v_exp_f32 %0, %1" : "=v"(r) : "v"(x));
    return r;
}

__device__ inline unsigned cvt_pk_bf16(float lo, float hi) {
    unsigned r;
    asm("v_cvt_pk_bf16_f32 %0, %1, %2" : "=v"(r) : "v"(lo), "v"(hi));
    return r;
}

// D(f32x4) += A(4 bf16: rows(lr) x k=lg*4+j) * B(4 bf16: k=lg*4+j x col=lr)
// Builtin-mediated so the compiler inserts MFMA wait-states (round-9 lesson:
// the hazard recognizer cannot see into inline-asm MFMA -> NaN).
#if __has_builtin(__builtin_amdgcn_mfma_f32_16x16x16bf16_1k)
__device__ inline void mfma16(f32x4& c, bf16x4 a, bf16x4 b) {
    c = __builtin_amdgcn_mfma_f32_16x16x16bf16_1k(a, b, c, 0, 0, 0);
}
#else
__device__ inline void mfma16(f32x4& c, bf16x4 a, bf16x4 b) {
    asm volatile("s_nop 2\n\tv_mfma_f32_16x16x16_bf16 %0, %1, %2, %0"
                 : "+v"(c) : "v"(a), "v"(b));
}
#endif

__device__ inline void gld_lds16(const void* g, void* l) {
    __builtin_amdgcn_global_load_lds((const __attribute__((address_space(1))) void*)g,
                                     (__attribute__((address_space(3))) void*)l,
                                     16, 0, 0);
}

// ---------------- prep: 4x W transpose (fp32 -> bf16^T), one launch ----------
__global__ __launch_bounds__(256) void prep_k(
    const float* __restrict__ Wq, const float* __restrict__ Wk,
    const float* __restrict__ Wv, const float* __restrict__ Wo,
    unsigned short* __restrict__ WqT, unsigned short* __restrict__ WkT,
    unsigned short* __restrict__ WvT, unsigned short* __restrict__ WoT)
{
    __shared__ float tile[32][33];
    const int j     = blockIdx.x >> 10;   // 0..3
    const int local = blockIdx.x & 1023;
    const float* W = (j == 0) ? Wq : (j == 1) ? Wk : (j == 2) ? Wv : Wo;
    unsigned short* Wt = (j == 0) ? WqT : (j == 1) ? WkT : (j == 2) ? WvT : WoT;
    const int bx = (local & 31) * 32;     // n block
    const int by = (local >> 5) * 32;     // k block
    const int tx = threadIdx.x & 31;
    const int ty = threadIdx.x >> 5;      // 0..7
#pragma unroll
    for (int i = 0; i < 32; i += 8)
        tile[ty + i][tx] = W[(size_t)(by + ty + i) * CH + bx + tx];
    __syncthreads();
#pragma unroll
    for (int i = 0; i < 32; i += 8)
        Wt[(size_t)(bx + ty + i) * CH + by + tx] = f2bf(tile[tx][ty + i]);
}

// ---------------- merged QKV projection GEMM (round-15 version, BK=64) -------
// A staged AS FP32 via global_load_lds with XOR-swizzled SOURCE (LDS linear,
// rule 21): chunk c pulls logical 16B slot (c&15)^(row&15); fragment reads
// use physical plo=(kk*8+lg*2)^lr, phi=plo^1. bf16 cvt at fragment read.
// Measured best across BK64/BK32/dbuf variants (rounds 15/16/20).
__global__ __launch_bounds__(256, 2)
void qkv_gemm(const float* __restrict__ Qf, const float* __restrict__ Kf,
              const float* __restrict__ Vf,
              const unsigned short* __restrict__ WqT, const unsigned short* __restrict__ WkT,
              const unsigned short* __restrict__ WvT,
              const float* __restrict__ bq, const float* __restrict__ bk,
              const float* __restrict__ bv,
              unsigned short* __restrict__ Qhb, unsigned short* __restrict__ Khb,
              unsigned short* __restrict__ Vtb)
{
    __shared__ float          As32[128 * 64];   // 32 KB, swizzled slots
    __shared__ unsigned short Bs[128 * 64];     // 16 KB
    const int job = blockIdx.y;
    const float* A32          = (job == 0) ? Qf  : (job == 1) ? Kf  : Vf;
    const unsigned short* Bt  = (job == 0) ? WqT : (job == 1) ? WkT : WvT;
    const float* bias         = (job == 0) ? bq  : (job == 1) ? bk  : bv;
    unsigned short* outp      = (job == 0) ? Qhb : (job == 1) ? Khb : Vtb;
    const float oscale        = (job == 0) ? QSCALE : 1.0f;

    const int tid  = threadIdx.x;
    const int lane = tid & 63;
    const int w    = tid >> 6;
    const int nbn  = GN >> 7;                 // 8
    const int nbm  = GM >> 7;                 // 64
    const int xcd  = blockIdx.x & 7;          // XCD m-slab swizzle (bijective)
    const int idx  = blockIdx.x >> 3;
    const int mb   = xcd * (nbm >> 3) + idx / nbn;
    const int nb   = idx % nbn;
    const int m0   = mb << 7;
    const int n0   = nb << 7;
    const int wrow = (w >> 1) << 6;
    const int wcol = (w & 1) << 6;
    const int lr   = lane & 15;
    const int lg   = lane >> 4;

    f32x4 acc[4][4] = {};

    for (int k0 = 0; k0 < GK; k0 += 64) {
        // A: 128 rows x 64 k fp32 = 2048 x 16B chunks (8/thread), source-swizzled
#pragma unroll
        for (int i = 0; i < 8; ++i) {
            int chunk = i * 256 + tid;
            int row  = chunk >> 4;            // 16 chunks per row (64 fp32)
            int l    = (chunk & 15) ^ (row & 15);   // logical 16B slot
            gld_lds16(A32 + (size_t)(m0 + row) * GK + k0 + l * 4,
                      (char*)As32 + chunk * 16);
        }
        // B: 128 rows x 64 k bf16 = 1024 x 16B chunks (4/thread)
#pragma unroll
        for (int i = 0; i < 4; ++i) {
            int chunk = i * 256 + tid;
            int row = chunk >> 3;
            int c8  = (chunk & 7) << 3;
            gld_lds16(Bt + (size_t)(n0 + row) * GK + k0 + c8, (char*)Bs + chunk * 16);
        }
        __syncthreads();
#pragma unroll
        for (int kk = 0; kk < 2; ++kk) {
            const int plo = ((kk << 3) | (lg << 1)) ^ lr;   // physical 16B slot
            const int phi = plo ^ 1;
            bf16x8 af[4], bfr[4];
#pragma unroll
            for (int f = 0; f < 4; ++f) {
                const float* base = As32 + (wrow + f * 16 + lr) * 64;
                f32x4 lo = *(const f32x4*)(base + plo * 4);
                f32x4 hi = *(const f32x4*)(base + phi * 4);
                union { bf16x8 v; unsigned u[4]; } cv;
                cv.u[0] = cvt_pk_bf16(lo[0], lo[1]);
                cv.u[1] = cvt_pk_bf16(lo[2], lo[3]);
                cv.u[2] = cvt_pk_bf16(hi[0], hi[1]);
                cv.u[3] = cvt_pk_bf16(hi[2], hi[3]);
                af[f] = cv.v;
            }
#pragma unroll
            for (int f = 0; f < 4; ++f)
                bfr[f] = *(const bf16x8*)(Bs + (wcol + f * 16 + lr) * 64 + kk * 32 + lg * 8);
#pragma unroll
            for (int i = 0; i < 4; ++i)
#pragma unroll
                for (int j = 0; j < 4; ++j)
                    acc[i][j] = __builtin_amdgcn_mfma_f32_16x16x32_bf16(af[i], bfr[j], acc[i][j], 0, 0, 0);
        }
        __syncthreads();
    }

    float bvals[4];
#pragma unroll
    for (int j = 0; j < 4; ++j) bvals[j] = bias[n0 + wcol + j * 16 + lr];

    if (job < 2) {
#pragma unroll
        for (int i = 0; i < 4; ++i) {
            const int mbase = m0 + wrow + i * 16 + lg * 4;
#pragma unroll
            for (int j = 0; j < 4; ++j) {
                const int n = n0 + wcol + j * 16 + lr;
                const int h = n >> 6, d = n & 63;
#pragma unroll
                for (int r = 0; r < 4; ++r) {
                    const int m = mbase + r;
                    const int b = m >> 11, t = m & 2047;
                    outp[((size_t)(b * NH + h) * SEQ + t) * HD + d] = f2bf((acc[i][j][r] + bvals[j]) * oscale);
                }
            }
        }
    } else {
#pragma unroll
        for (int i = 0; i < 4; ++i) {
            const int mbase = m0 + wrow + i * 16 + lg * 4;
#pragma unroll
            for (int j = 0; j < 4; ++j) {
                const int n = n0 + wcol + j * 16 + lr;
                const int h = n >> 6, d = n & 63;
                const int b = mbase >> 11, t = mbase & 2047;
                union { unsigned short s[4]; uint2 v; } pk;
#pragma unroll
                for (int r = 0; r < 4; ++r) pk.s[r] = f2bf(acc[i][j][r] + bvals[j]);
                *(uint2*)(outp + ((size_t)(b * NH + h) * HD + d) * SEQ + t) = pk.v;
            }
        }
    }
}

// ---------------- output projection GEMM (fp32 out) ----------------
__global__ __launch_bounds__(256, 2)
void gemm_out(const unsigned short* __restrict__ A,
              const unsigned short* __restrict__ Bt,
              const float* __restrict__ bias,
              float* __restrict__ out)
{
    __shared__ unsigned short As[128 * 64];
    __shared__ unsigned short Bs[128 * 64];
    const int tid  = threadIdx.x;
    const int lane = tid & 63;
    const int w    = tid >> 6;
    const int nbn  = GN >> 7;
    const int nbm  = GM >> 7;
    const int xcd  = blockIdx.x & 7;
    const int idx  = blockIdx.x >> 3;
    const int mb   = xcd * (nbm >> 3) + idx / nbn;
    const int nb   = idx % nbn;
    const int m0   = mb << 7;
    const int n0   = nb << 7;
    const int wrow = (w >> 1) << 6;
    const int wcol = (w & 1) << 6;
    const int lr   = lane & 15;
    const int lg   = lane >> 4;

    f32x4 acc[4][4] = {};

    for (int k0 = 0; k0 < GK; k0 += 64) {
#pragma unroll
        for (int i = 0; i < 4; ++i) {
            int chunk = i * 256 + tid;
            int row = chunk >> 3;
            int c8  = (chunk & 7) << 3;
            gld_lds16(A  + (size_t)(m0 + row) * GK + k0 + c8, (char*)As + chunk * 16);
            gld_lds16(Bt + (size_t)(n0 + row) * GK + k0 + c8, (char*)Bs + chunk * 16);
        }
        __syncthreads();
#pragma unroll
        for (int kk = 0; kk < 2; ++kk) {
            bf16x8 af[4], bfr[4];
#pragma unroll
            for (int f = 0; f < 4; ++f)
                af[f] = *(const bf16x8*)(As + (wrow + f * 16 + lr) * 64 + kk * 32 + lg * 8);
#pragma unroll
            for (int f = 0; f < 4; ++f)
                bfr[f] = *(const bf16x8*)(Bs + (wcol + f * 16 + lr) * 64 + kk * 32 + lg * 8);
#pragma unroll
            for (int i = 0; i < 4; ++i)
#pragma unroll
                for (int j = 0; j < 4; ++j)
                    acc[i][j] = __builtin_amdgcn_mfma_f32_16x16x32_bf16(af[i], bfr[j], acc[i][j], 0, 0, 0);
        }
        __syncthreads();
    }

    float bvals[4];
#pragma unroll
    for (int j = 0; j < 4; ++j) bvals[j] = bias[n0 + wcol + j * 16 + lr];

#pragma unroll
    for (int i = 0; i < 4; ++i) {
        const int mbase = m0 + wrow + i * 16 + lg * 4;
#pragma unroll
        for (int j = 0; j < 4; ++j) {
            const int n = n0 + wcol + j * 16 + lr;
#pragma unroll
            for (int r = 0; r < 4; ++r)
                out[(size_t)(mbase + r) * GN + n] = acc[i][j][r] + bvals[j];
        }
    }
}

// ---------------- flash attention (64-row, T13 defer-max THR=8) -------------
__global__ __launch_bounds__(256, 4)
void attn_k(const unsigned short* __restrict__ Qh,   // (BH, T, 64), pre-scaled
            const unsigned short* __restrict__ Kh,   // (BH, T, 64)
            const unsigned short* __restrict__ Vt,   // (BH, 64, T)
            unsigned short* __restrict__ O) {        // (B, T, H*64)
    __shared__ unsigned short Ks[2][64 * 64];
    __shared__ unsigned short Vs[2][64 * 64];   // [d][kv], pair-swizzled
    const int bh    = blockIdx.x;
    const int qtile = 31 - blockIdx.y;          // longest first
    const int q0    = qtile << 6;
    const int tid  = threadIdx.x;
    const int lane = tid & 63;
    const int w    = tid >> 6;
    const int lr   = lane & 15;
    const int lg   = lane >> 4;
    const int qw   = q0 + w * 16;               // wave's first q row

    bf16x4 ones4;
#pragma unroll
    for (int j = 0; j < 4; ++j) ones4[j] = (short)0x3F80;   // bf16 1.0

    bf16x8 qf[2];
#pragma unroll
    for (int kk = 0; kk < 2; ++kk)
        qf[kk] = *(const bf16x8*)(Qh + ((size_t)bh * SEQ + qw + lr) * HD + kk * 32 + lg * 8);

    float mrun = -3e38f;
    f32x4 ot[4] = {};    // O^T: ot[dd] col=lr(q), row=lg*4+r -> d=dd*16+lg*4+r
    f32x4 osum = {};     // all 4 rows equal: sum_k P[q][k]

    const int nkt = qtile + 1;

#define STAGE(KT, B) do {                                                          \
        const int kv_ = (KT) << 6;                                                 \
        _Pragma("unroll")                                                          \
        for (int i_ = 0; i_ < 2; ++i_) {                                           \
            int c_ = i_ * 256 + tid;                                               \
            int row_ = c_ >> 3;                                                    \
            int sk_ = (((c_ & 7) ^ (row_ & 7)) << 3);                              \
            int sv_ = (((c_ & 7) ^ ((row_ >> 1) & 7)) << 3);                       \
            gld_lds16(Kh + ((size_t)bh * SEQ + kv_ + row_) * HD + sk_,             \
                      (char*)Ks[B] + c_ * 16);                                     \
            gld_lds16(Vt + ((size_t)bh * HD + row_) * SEQ + kv_ + sv_,             \
                      (char*)Vs[B] + c_ * 16);                                     \
        }                                                                          \
    } while (0)

    STAGE(0, 0);
    __syncthreads();

    for (int kt = 0; kt < nkt; ++kt) {
        if (kt + 1 < nkt) STAGE(kt + 1, (kt + 1) & 1);
        const unsigned short* Kc = Ks[kt & 1];
        const unsigned short* Vc = Vs[kt & 1];
        const int kv0 = kt << 6;

        // ---- QK^T, swapped operands: s[f] holds S[q=qw+lr][kv0+f*16+lg*4+r] ----
        f32x4 s[4] = {};
#pragma unroll
        for (int kk = 0; kk < 2; ++kk) {
            const int u = (((kk << 2) | lg) ^ (lr & 7)) << 3;
#pragma unroll
            for (int f = 0; f < 4; ++f) {
                bf16x8 kb = *(const bf16x8*)(Kc + (f * 16 + lr) * 64 + u);
                s[f] = __builtin_amdgcn_mfma_f32_16x16x32_bf16(kb, qf[kk], s[f], 0, 0, 0);
            }
        }

        // ---- causal mask (diag tile only) + row max (scalar per lane) ----
        float rmax = -3e38f;
        if (kv0 + 63 <= qw) {
#pragma unroll
            for (int f = 0; f < 4; ++f)
#pragma unroll
                for (int r = 0; r < 4; ++r) rmax = fmaxf(rmax, s[f][r]);
        } else {
            const int q = qw + lr;
#pragma unroll
            for (int f = 0; f < 4; ++f)
#pragma unroll
                for (int r = 0; r < 4; ++r) {
                    const int kv = kv0 + f * 16 + lg * 4 + r;
                    float v = (kv > q) ? -3e38f : s[f][r];
                    s[f][r] = v;
                    rmax = fmaxf(rmax, v);
                }
        }
        // reduce across the 4 lg-groups owning this q row
        rmax = fmaxf(rmax, __shfl_xor(rmax, 16));
        rmax = fmaxf(rmax, __shfl_xor(rmax, 32));

        // ---- T13 deferred rescale: only when max grows past THR=8 ----
        if (!__all(rmax <= mrun + 8.0f)) {
            float mn = fmaxf(mrun, rmax);
            float c  = fast_exp2(mrun - mn);
            mrun = mn;
            osum *= c;
#pragma unroll
            for (int dd = 0; dd < 4; ++dd) ot[dd] *= c;
        }

        // ---- P = 2^(s-m), pack to bf16 in-register, PV + denominator ----
#pragma unroll
        for (int f = 0; f < 4; ++f) {
#pragma unroll
            for (int r = 0; r < 4; ++r)
                s[f][r] = fast_exp2(s[f][r] - mrun);
            union { bf16x4 v; unsigned u[2]; } pb;
            pb.u[0] = cvt_pk_bf16(s[f][0], s[f][1]);
            pb.u[1] = cvt_pk_bf16(s[f][2], s[f][3]);
            mfma16(osum, ones4, pb.v);
#pragma unroll
            for (int dd = 0; dd < 4; ++dd) {
                const int vcol = ((((f << 1) | (lg >> 1)) ^ (lr >> 1)) << 3) | ((lg & 1) << 2);
                bf16x4 va = *(const bf16x4*)(Vc + (dd * 16 + lr) * 64 + vcol);
                mfma16(ot[dd], va, pb.v);
            }
        }
        __syncthreads();
    }
#undef STAGE

    const int b = bh >> 4, h = bh & 15;
    const float inv = 1.0f / osum[0];
    const int t = qw + lr;
#pragma unroll
    for (int dd = 0; dd < 4; ++dd) {
        union { unsigned short s4[4]; uint2 v; } pk;
#pragma unroll
        for (int r = 0; r < 4; ++r) pk.s4[r] = f2bf(ot[dd][r] * inv);
        *(uint2*)(O + ((size_t)b * SEQ + t) * CH + h * HD + dd * 16 + lg * 4) = pk.v;
    }
}

extern "C" void kernel_launch(void* const* d_in, const int* in_sizes, int n_in,
                              void* d_out, int out_size, void* d_ws, size_t ws_size,
                              hipStream_t stream) {
    const float* Q  = (const float*)d_in[0];
    const float* K  = (const float*)d_in[1];
    const float* V  = (const float*)d_in[2];
    // d_in[3] = mask: always causal triu(k=1); applied analytically in attn_k
    const float* Wq = (const float*)d_in[4];
    const float* bq = (const float*)d_in[5];
    const float* Wk = (const float*)d_in[6];
    const float* bk = (const float*)d_in[7];
    const float* Wv = (const float*)d_in[8];
    const float* bv = (const float*)d_in[9];
    const float* Wo = (const float*)d_in[10];
    const float* bo = (const float*)d_in[11];
    float* out = (float*)d_out;

    const size_t SZ_ACT = (size_t)BATCH * SEQ * CH;  // 8388608
    const size_t SZ_W   = (size_t)CH * CH;           // 1048576

    char* p = (char*)d_ws;
    unsigned short* WqT = (unsigned short*)p; p += SZ_W * 2;
    unsigned short* WkT = (unsigned short*)p; p += SZ_W * 2;
    unsigned short* WvT = (unsigned short*)p; p += SZ_W * 2;
    unsigned short* WoT = (unsigned short*)p; p += SZ_W * 2;
    unsigned short* Qhb = (unsigned short*)p; p += SZ_ACT * 2;
    unsigned short* Khb = (unsigned short*)p; p += SZ_ACT * 2;
    unsigned short* Vtb = (unsigned short*)p; p += SZ_ACT * 2;
    unsigned short* Ob  = (unsigned short*)p; p += SZ_ACT * 2;

    prep_k<<<4096, 256, 0, stream>>>(Wq, Wk, Wv, Wo, WqT, WkT, WvT, WoT);

    qkv_gemm<<<dim3((GM / 128) * (GN / 128), 3), 256, 0, stream>>>(
        Q, K, V, WqT, WkT, WvT, bq, bk, bv, Qhb, Khb, Vtb);

    attn_k<<<dim3(BATCH * NH, SEQ / 64), 256, 0, stream>>>(Qhb, Khb, Vtb, Ob);

    gemm_out<<<(GM / 128) * (GN / 128), 256, 0, stream>>>(Ob, WoT, bo, out);
}